// Round 1
// baseline (3178.687 us; speedup 1.0000x reference)
//
#include <hip/hip_runtime.h>
#include <math.h>

#define N_ATOMS 10000
#define N_EDGES 320000
#define C 32
#define NB 8
#define NCOMB 11

__global__ __launch_bounds__(256) void TensorAggregateLayer_edge_kernel(
    const float* __restrict__ x0, const float* __restrict__ x1,
    const float* __restrict__ x2, const float* __restrict__ pos,
    const float* __restrict__ W, const float* __restrict__ b,
    const int* __restrict__ idx_i, const int* __restrict__ idx_j,
    float* __restrict__ out)
{
    int tid = blockIdx.x * blockDim.x + threadIdx.x;
    int e = tid >> 5;          // 32 threads per edge, one per channel
    int c = tid & 31;
    if (e >= N_EDGES) return;

    int i = idx_i[e], j = idx_j[e];

    float rx = pos[3*j+0] - pos[3*i+0];
    float ry = pos[3*j+1] - pos[3*i+1];
    float rz = pos[3*j+2] - pos[3*i+2];
    float d2 = rx*rx + ry*ry + rz*rz + 1e-12f;
    float d  = sqrtf(d2);
    float invd = 1.0f / d;
    float ux = rx*invd, uy = ry*invd, uz = rz*invd;

    // Bessel RBF with cosine cutoff
    const float PI = 3.14159265358979323846f;
    const float RC = 5.0f;
    float fc   = 0.5f * (cosf(PI * fminf(d, RC) / RC) + 1.0f);
    float pref = sqrtf(2.0f / RC) * invd * fc;
    float phase = PI * d / RC;
    float rbf[NB];
    #pragma unroll
    for (int nb = 0; nb < NB; ++nb)
        rbf[nb] = pref * sinf((float)(nb + 1) * phase);

    // fn_k[c] = (rbf . W[k][:,c] + b[k][c]) / NORM
    float fn[NCOMB];
    #pragma unroll
    for (int k = 0; k < NCOMB; ++k) {
        float acc = b[k*C + c];
        #pragma unroll
        for (int nb = 0; nb < NB; ++nb)
            acc += rbf[nb] * W[(k*NB + nb)*C + c];
        fn[k] = acc * (1.0f / 32.0f);
    }

    // gather neighbor features (channel c)
    float v0 = x0[j*C + c];
    float v1[3], v2[9];
    #pragma unroll
    for (int m = 0; m < 3; ++m) v1[m] = x1[(j*C + c)*3 + m];
    #pragma unroll
    for (int m = 0; m < 9; ++m) v2[m] = x2[(j*C + c)*9 + m];

    float u[3] = {ux, uy, uz};
    float t2[3];
    #pragma unroll
    for (int a = 0; a < 3; ++a)
        t2[a] = v2[a*3+0]*ux + v2[a*3+1]*uy + v2[a*3+2]*uz;
    float s1 = v1[0]*ux + v1[1]*uy + v1[2]*uz;
    float s2 = t2[0]*ux + t2[1]*uy + t2[2]*uz;

    float* out0 = out;
    float* out1 = out + N_ATOMS * C;
    float* out2 = out + N_ATOMS * C * 4;

    atomicAdd(&out0[i*C + c], fn[0]*v0 + fn[4]*s1 + fn[9]*s2);

    #pragma unroll
    for (int m = 0; m < 3; ++m)
        atomicAdd(&out1[(i*C + c)*3 + m],
                  fn[1]*v0*u[m] + fn[3]*v1[m] + fn[6]*s1*u[m] + fn[8]*t2[m]);

    #pragma unroll
    for (int a = 0; a < 3; ++a) {
        float ca = fn[2]*v0*u[a] + fn[5]*v1[a] + fn[10]*t2[a];
        #pragma unroll
        for (int bb = 0; bb < 3; ++bb)
            atomicAdd(&out2[(i*C + c)*9 + a*3 + bb],
                      ca*u[bb] + fn[7]*v2[a*3 + bb]);
    }
}

extern "C" void kernel_launch(void* const* d_in, const int* in_sizes, int n_in,
                              void* d_out, int out_size, void* d_ws, size_t ws_size,
                              hipStream_t stream) {
    const float* x0    = (const float*)d_in[0];
    const float* x1    = (const float*)d_in[1];
    const float* x2    = (const float*)d_in[2];
    const float* pos   = (const float*)d_in[3];
    const float* W     = (const float*)d_in[4];
    const float* b     = (const float*)d_in[5];
    const int*   idx_i = (const int*)d_in[6];
    const int*   idx_j = (const int*)d_in[7];
    float* out = (float*)d_out;

    hipMemsetAsync(d_out, 0, (size_t)out_size * sizeof(float), stream);

    int total_threads = N_EDGES * 32;
    int block = 256;
    int grid = (total_threads + block - 1) / block;
    TensorAggregateLayer_edge_kernel<<<grid, block, 0, stream>>>(
        x0, x1, x2, pos, W, b, idx_i, idx_j, out);
}

// Round 2
// 180.871 us; speedup vs baseline: 17.5743x; 17.5743x over previous
//
#include <hip/hip_runtime.h>
#include <math.h>

#define N_ATOMS 10000
#define N_EDGES 320000
#define C 32
#define NB 8
#define NCOMB 11
#define ED_STRIDE 12   // floats per edge record: u(3) rbf(8) j(1)

// ---- ws layout (byte offsets) ----
#define WS_COUNTS   0u
#define WS_OFFSETS  40064u
#define WS_CURSOR   80128u
#define WS_ELIST    120192u
#define WS_EDATA    1400320u
#define WS_NEEDED   (WS_EDATA + (size_t)N_EDGES * ED_STRIDE * 4u)

// ---------------- kernel A: per-edge precompute + histogram ----------------
__global__ __launch_bounds__(256) void edge_prep_kernel(
    const float* __restrict__ pos, const int* __restrict__ idx_i,
    const int* __restrict__ idx_j, float* __restrict__ edge_data,
    int* __restrict__ counts)
{
    int e = blockIdx.x * blockDim.x + threadIdx.x;
    if (e >= N_EDGES) return;
    int i = idx_i[e], j = idx_j[e];

    float rx = pos[3*j+0] - pos[3*i+0];
    float ry = pos[3*j+1] - pos[3*i+1];
    float rz = pos[3*j+2] - pos[3*i+2];
    float d  = sqrtf(rx*rx + ry*ry + rz*rz + 1e-12f);
    float invd = 1.0f / d;
    float ux = rx*invd, uy = ry*invd, uz = rz*invd;

    const float PI = 3.14159265358979323846f;
    const float RC = 5.0f;
    float fc    = 0.5f * (cosf(PI * fminf(d, RC) / RC) + 1.0f);
    float pref  = sqrtf(2.0f / RC) * invd * fc;
    float phase = PI * d / RC;
    float rbf[NB];
    #pragma unroll
    for (int nb = 0; nb < NB; ++nb)
        rbf[nb] = pref * sinf((float)(nb + 1) * phase);

    float4* ed = (float4*)(edge_data + (size_t)e * ED_STRIDE);
    ed[0] = make_float4(ux, uy, uz, rbf[0]);
    ed[1] = make_float4(rbf[1], rbf[2], rbf[3], rbf[4]);
    ed[2] = make_float4(rbf[5], rbf[6], rbf[7], __int_as_float(j));

    atomicAdd(&counts[i], 1);
}

// ---------------- kernel B: single-block exclusive scan (10000 -> 10001) ----
__global__ __launch_bounds__(256) void scan_kernel(
    const int* __restrict__ counts, int* __restrict__ offsets)
{
    __shared__ int part[256];
    const int PER = 40;                      // 256*40 >= 10000
    int t = threadIdx.x;
    int base = t * PER;
    int s = 0;
    for (int k = 0; k < PER; ++k) {
        int idx = base + k;
        s += (idx < N_ATOMS) ? counts[idx] : 0;
    }
    part[t] = s;
    __syncthreads();
    for (int off = 1; off < 256; off <<= 1) {
        int v = (t >= off) ? part[t - off] : 0;
        __syncthreads();
        part[t] += v;
        __syncthreads();
    }
    int run = (t == 0) ? 0 : part[t - 1];
    for (int k = 0; k < PER; ++k) {
        int idx = base + k;
        if (idx < N_ATOMS) { offsets[idx] = run; run += counts[idx]; }
    }
    if (t == 255) offsets[N_ATOMS] = part[255];
}

// ---------------- kernel C: bucket edge ids into CSR ----------------
__global__ __launch_bounds__(256) void bucket_kernel(
    const int* __restrict__ idx_i, const int* __restrict__ offsets,
    int* __restrict__ cursor, int* __restrict__ elist)
{
    int e = blockIdx.x * blockDim.x + threadIdx.x;
    if (e >= N_EDGES) return;
    int i = idx_i[e];
    int pos = offsets[i] + atomicAdd(&cursor[i], 1);
    elist[pos] = e;
}

// ---------------- kernel D: gather — one wave per atom ----------------
__global__ __launch_bounds__(256, 2) void gather_kernel(
    const float* __restrict__ x0, const float* __restrict__ x1,
    const float* __restrict__ x2, const float* __restrict__ W,
    const float* __restrict__ b, const int* __restrict__ offsets,
    const int* __restrict__ elist, const float* __restrict__ edge_data,
    float* __restrict__ out)
{
    int wave = (blockIdx.x * blockDim.x + threadIdx.x) >> 6;
    int lane = threadIdx.x & 63;
    int c = lane & 31;     // channel
    int h = lane >> 5;     // edge-half
    if (wave >= N_ATOMS) return;
    int a = wave;

    // hoist W column c and bias into registers (reused for every edge)
    float Wc[NCOMB][NB], bc[NCOMB];
    #pragma unroll
    for (int k = 0; k < NCOMB; ++k) {
        bc[k] = b[k*C + c];
        #pragma unroll
        for (int nb = 0; nb < NB; ++nb)
            Wc[k][nb] = W[(k*NB + nb)*C + c];
    }

    float acc[13];
    #pragma unroll
    for (int q = 0; q < 13; ++q) acc[q] = 0.0f;

    int start = offsets[a], end = offsets[a + 1];
    for (int p = start + h; p < end; p += 2) {
        int e = elist[p];
        const float4* ed = (const float4*)(edge_data + (size_t)e * ED_STRIDE);
        float4 Av = ed[0], Bv = ed[1], Cv = ed[2];
        float ux = Av.x, uy = Av.y, uz = Av.z;
        float rbf[NB] = {Av.w, Bv.x, Bv.y, Bv.z, Bv.w, Cv.x, Cv.y, Cv.z};
        int j = __float_as_int(Cv.w);

        float fn[NCOMB];
        #pragma unroll
        for (int k = 0; k < NCOMB; ++k) {
            float t = bc[k];
            #pragma unroll
            for (int nb = 0; nb < NB; ++nb)
                t = fmaf(rbf[nb], Wc[k][nb], t);
            fn[k] = t * (1.0f / 32.0f);
        }

        float v0 = x0[j*C + c];
        float v1[3], v2[9];
        #pragma unroll
        for (int m = 0; m < 3; ++m) v1[m] = x1[(j*C + c)*3 + m];
        #pragma unroll
        for (int m = 0; m < 9; ++m) v2[m] = x2[(j*C + c)*9 + m];

        float u[3] = {ux, uy, uz};
        float t2[3];
        #pragma unroll
        for (int q = 0; q < 3; ++q)
            t2[q] = v2[q*3+0]*ux + v2[q*3+1]*uy + v2[q*3+2]*uz;
        float s1 = v1[0]*ux + v1[1]*uy + v1[2]*uz;
        float s2 = t2[0]*ux + t2[1]*uy + t2[2]*uz;

        acc[0] += fn[0]*v0 + fn[4]*s1 + fn[9]*s2;
        #pragma unroll
        for (int m = 0; m < 3; ++m)
            acc[1+m] += fn[1]*v0*u[m] + fn[3]*v1[m] + fn[6]*s1*u[m] + fn[8]*t2[m];
        #pragma unroll
        for (int q = 0; q < 3; ++q) {
            float ca = fn[2]*v0*u[q] + fn[5]*v1[q] + fn[10]*t2[q];
            #pragma unroll
            for (int bb = 0; bb < 3; ++bb)
                acc[4 + q*3 + bb] += ca*u[bb] + fn[7]*v2[q*3 + bb];
        }
    }

    // combine the two edge-halves
    #pragma unroll
    for (int q = 0; q < 13; ++q)
        acc[q] += __shfl_xor(acc[q], 32);

    if (h == 0) {
        float* out0 = out;
        float* out1 = out + N_ATOMS * C;
        float* out2 = out + N_ATOMS * C * 4;
        out0[a*C + c] = acc[0];
        #pragma unroll
        for (int m = 0; m < 3; ++m) out1[(a*C + c)*3 + m] = acc[1+m];
        #pragma unroll
        for (int q = 0; q < 9; ++q) out2[(a*C + c)*9 + q] = acc[4+q];
    }
}

// ---------------- fallback: round-0 atomic path ----------------
__global__ __launch_bounds__(256) void edge_atomic_kernel(
    const float* __restrict__ x0, const float* __restrict__ x1,
    const float* __restrict__ x2, const float* __restrict__ pos,
    const float* __restrict__ W, const float* __restrict__ b,
    const int* __restrict__ idx_i, const int* __restrict__ idx_j,
    float* __restrict__ out)
{
    int tid = blockIdx.x * blockDim.x + threadIdx.x;
    int e = tid >> 5;
    int c = tid & 31;
    if (e >= N_EDGES) return;
    int i = idx_i[e], j = idx_j[e];
    float rx = pos[3*j+0] - pos[3*i+0];
    float ry = pos[3*j+1] - pos[3*i+1];
    float rz = pos[3*j+2] - pos[3*i+2];
    float d  = sqrtf(rx*rx + ry*ry + rz*rz + 1e-12f);
    float invd = 1.0f / d;
    float ux = rx*invd, uy = ry*invd, uz = rz*invd;
    const float PI = 3.14159265358979323846f;
    const float RC = 5.0f;
    float fc   = 0.5f * (cosf(PI * fminf(d, RC) / RC) + 1.0f);
    float pref = sqrtf(2.0f / RC) * invd * fc;
    float phase = PI * d / RC;
    float rbf[NB];
    #pragma unroll
    for (int nb = 0; nb < NB; ++nb) rbf[nb] = pref * sinf((float)(nb+1) * phase);
    float fn[NCOMB];
    #pragma unroll
    for (int k = 0; k < NCOMB; ++k) {
        float acc = b[k*C + c];
        #pragma unroll
        for (int nb = 0; nb < NB; ++nb) acc += rbf[nb] * W[(k*NB + nb)*C + c];
        fn[k] = acc * (1.0f / 32.0f);
    }
    float v0 = x0[j*C + c];
    float v1[3], v2[9];
    #pragma unroll
    for (int m = 0; m < 3; ++m) v1[m] = x1[(j*C + c)*3 + m];
    #pragma unroll
    for (int m = 0; m < 9; ++m) v2[m] = x2[(j*C + c)*9 + m];
    float u[3] = {ux, uy, uz};
    float t2[3];
    #pragma unroll
    for (int q = 0; q < 3; ++q)
        t2[q] = v2[q*3+0]*ux + v2[q*3+1]*uy + v2[q*3+2]*uz;
    float s1 = v1[0]*ux + v1[1]*uy + v1[2]*uz;
    float s2 = t2[0]*ux + t2[1]*uy + t2[2]*uz;
    float* out0 = out;
    float* out1 = out + N_ATOMS * C;
    float* out2 = out + N_ATOMS * C * 4;
    atomicAdd(&out0[i*C + c], fn[0]*v0 + fn[4]*s1 + fn[9]*s2);
    #pragma unroll
    for (int m = 0; m < 3; ++m)
        atomicAdd(&out1[(i*C + c)*3 + m],
                  fn[1]*v0*u[m] + fn[3]*v1[m] + fn[6]*s1*u[m] + fn[8]*t2[m]);
    #pragma unroll
    for (int q = 0; q < 3; ++q) {
        float ca = fn[2]*v0*u[q] + fn[5]*v1[q] + fn[10]*t2[q];
        #pragma unroll
        for (int bb = 0; bb < 3; ++bb)
            atomicAdd(&out2[(i*C + c)*9 + q*3 + bb], ca*u[bb] + fn[7]*v2[q*3 + bb]);
    }
}

extern "C" void kernel_launch(void* const* d_in, const int* in_sizes, int n_in,
                              void* d_out, int out_size, void* d_ws, size_t ws_size,
                              hipStream_t stream) {
    const float* x0    = (const float*)d_in[0];
    const float* x1    = (const float*)d_in[1];
    const float* x2    = (const float*)d_in[2];
    const float* pos   = (const float*)d_in[3];
    const float* W     = (const float*)d_in[4];
    const float* b     = (const float*)d_in[5];
    const int*   idx_i = (const int*)d_in[6];
    const int*   idx_j = (const int*)d_in[7];
    float* out = (float*)d_out;

    if (ws_size >= WS_NEEDED) {
        char* ws = (char*)d_ws;
        int*   counts    = (int*)(ws + WS_COUNTS);
        int*   offsets   = (int*)(ws + WS_OFFSETS);
        int*   cursor    = (int*)(ws + WS_CURSOR);
        int*   elist     = (int*)(ws + WS_ELIST);
        float* edge_data = (float*)(ws + WS_EDATA);

        hipMemsetAsync(counts, 0, N_ATOMS * sizeof(int), stream);
        hipMemsetAsync(cursor, 0, N_ATOMS * sizeof(int), stream);

        int eb = 256, eg = (N_EDGES + eb - 1) / eb;
        edge_prep_kernel<<<eg, eb, 0, stream>>>(pos, idx_i, idx_j, edge_data, counts);
        scan_kernel<<<1, 256, 0, stream>>>(counts, offsets);
        bucket_kernel<<<eg, eb, 0, stream>>>(idx_i, offsets, cursor, elist);

        int waves_per_block = 256 / 64;
        int grid = (N_ATOMS + waves_per_block - 1) / waves_per_block;
        gather_kernel<<<grid, 256, 0, stream>>>(x0, x1, x2, W, b,
                                                offsets, elist, edge_data, out);
    } else {
        hipMemsetAsync(d_out, 0, (size_t)out_size * sizeof(float), stream);
        int total_threads = N_EDGES * 32;
        int block = 256;
        int grid = (total_threads + block - 1) / block;
        edge_atomic_kernel<<<grid, block, 0, stream>>>(
            x0, x1, x2, pos, W, b, idx_i, idx_j, out);
    }
}

// Round 3
// 173.025 us; speedup vs baseline: 18.3713x; 1.0454x over previous
//
#include <hip/hip_runtime.h>
#include <math.h>

#define N_ATOMS 10000
#define N_EDGES 320000
#define C 32
#define NB 8
#define NCOMB 11
#define ED_STRIDE 12   // floats per edge record: u(3) rbf(8) j(1)

// ---- ws layout (byte offsets) ----
#define WS_COUNTS   0u
#define WS_OFFSETS  40064u
#define WS_CURSOR   80128u
#define WS_EDATA    120192u
#define WS_NEEDED   (WS_EDATA + (size_t)N_EDGES * ED_STRIDE * 4u)

// ---------------- kernel 1: histogram ----------------
__global__ __launch_bounds__(256) void hist_kernel(
    const int* __restrict__ idx_i, int* __restrict__ counts)
{
    int e = blockIdx.x * blockDim.x + threadIdx.x;
    if (e >= N_EDGES) return;
    atomicAdd(&counts[idx_i[e]], 1);
}

// ---------------- kernel 2: single-block exclusive scan; cursor = copy ----
__global__ __launch_bounds__(256) void scan_kernel(
    const int* __restrict__ counts, int* __restrict__ offsets,
    int* __restrict__ cursor)
{
    __shared__ int part[256];
    const int PER = 40;                      // 256*40 >= 10000
    int t = threadIdx.x;
    int base = t * PER;
    int s = 0;
    for (int k = 0; k < PER; ++k) {
        int idx = base + k;
        s += (idx < N_ATOMS) ? counts[idx] : 0;
    }
    part[t] = s;
    __syncthreads();
    for (int off = 1; off < 256; off <<= 1) {
        int v = (t >= off) ? part[t - off] : 0;
        __syncthreads();
        part[t] += v;
        __syncthreads();
    }
    int run = (t == 0) ? 0 : part[t - 1];
    for (int k = 0; k < PER; ++k) {
        int idx = base + k;
        if (idx < N_ATOMS) { offsets[idx] = run; cursor[idx] = run; run += counts[idx]; }
    }
    if (t == 255) offsets[N_ATOMS] = part[255];
}

// ---------------- kernel 3: per-edge precompute, scatter record to CSR slot --
__global__ __launch_bounds__(256) void prep_scatter_kernel(
    const float* __restrict__ pos, const int* __restrict__ idx_i,
    const int* __restrict__ idx_j, int* __restrict__ cursor,
    float* __restrict__ edata)
{
    int e = blockIdx.x * blockDim.x + threadIdx.x;
    if (e >= N_EDGES) return;
    int i = idx_i[e], j = idx_j[e];

    float rx = pos[3*j+0] - pos[3*i+0];
    float ry = pos[3*j+1] - pos[3*i+1];
    float rz = pos[3*j+2] - pos[3*i+2];
    float d  = sqrtf(rx*rx + ry*ry + rz*rz + 1e-12f);
    float invd = 1.0f / d;
    float ux = rx*invd, uy = ry*invd, uz = rz*invd;

    const float PI = 3.14159265358979323846f;
    const float RC = 5.0f;
    float fc    = 0.5f * (cosf(PI * fminf(d, RC) / RC) + 1.0f);
    float pref  = sqrtf(2.0f / RC) * invd * fc;
    float phase = PI * d / RC;
    float rbf[NB];
    #pragma unroll
    for (int nb = 0; nb < NB; ++nb)
        rbf[nb] = pref * sinf((float)(nb + 1) * phase);

    int slot = atomicAdd(&cursor[i], 1);
    float4* dst = (float4*)(edata + (size_t)slot * ED_STRIDE);
    dst[0] = make_float4(ux, uy, uz, rbf[0]);
    dst[1] = make_float4(rbf[1], rbf[2], rbf[3], rbf[4]);
    dst[2] = make_float4(rbf[5], rbf[6], rbf[7], __int_as_float(j));
}

// ---------------- kernel 4: gather — one wave per atom ----------------
__global__ __launch_bounds__(256, 2) void gather_kernel(
    const float* __restrict__ x0, const float* __restrict__ x1,
    const float* __restrict__ x2, const float* __restrict__ W,
    const float* __restrict__ b, const int* __restrict__ offsets,
    const float* __restrict__ edata, float* __restrict__ out)
{
    int wave = (blockIdx.x * blockDim.x + threadIdx.x) >> 6;
    int lane = threadIdx.x & 63;
    int c = lane & 31;     // channel
    int h = lane >> 5;     // edge-half
    if (wave >= N_ATOMS) return;
    int a = wave;

    // hoist W column c (pre-scaled by 1/NORM) into registers and PIN them
    float Wc[NCOMB][NB], bc[NCOMB];
    #pragma unroll
    for (int k = 0; k < NCOMB; ++k) {
        bc[k] = b[k*C + c] * (1.0f / 32.0f);
        #pragma unroll
        for (int nb = 0; nb < NB; ++nb)
            Wc[k][nb] = W[(k*NB + nb)*C + c] * (1.0f / 32.0f);
    }
    #pragma unroll
    for (int k = 0; k < NCOMB; ++k) {
        asm volatile("" : "+v"(bc[k]));
        #pragma unroll
        for (int nb = 0; nb < NB; ++nb)
            asm volatile("" : "+v"(Wc[k][nb]));
    }

    float acc[13];
    #pragma unroll
    for (int q = 0; q < 13; ++q) acc[q] = 0.0f;

    int start = offsets[a], end = offsets[a + 1];

#define EDGE_BODY(P)                                                          \
    {                                                                         \
        const float4* ed = (const float4*)(edata + (size_t)(P) * ED_STRIDE);  \
        float4 Av = ed[0], Bv = ed[1], Cv = ed[2];                            \
        float ux = Av.x, uy = Av.y, uz = Av.z;                                \
        float rbf[NB] = {Av.w, Bv.x, Bv.y, Bv.z, Bv.w, Cv.x, Cv.y, Cv.z};     \
        int j = __float_as_int(Cv.w);                                         \
        float fn[NCOMB];                                                      \
        _Pragma("unroll")                                                     \
        for (int k = 0; k < NCOMB; ++k) {                                     \
            float t = bc[k];                                                  \
            _Pragma("unroll")                                                 \
            for (int nb = 0; nb < NB; ++nb)                                   \
                t = fmaf(rbf[nb], Wc[k][nb], t);                              \
            fn[k] = t;                                                        \
        }                                                                     \
        float v0 = x0[j*C + c];                                               \
        float v1[3], v2[9];                                                   \
        _Pragma("unroll")                                                     \
        for (int m = 0; m < 3; ++m) v1[m] = x1[(j*C + c)*3 + m];              \
        _Pragma("unroll")                                                     \
        for (int m = 0; m < 9; ++m) v2[m] = x2[(j*C + c)*9 + m];              \
        float u[3] = {ux, uy, uz};                                            \
        float t2[3];                                                          \
        _Pragma("unroll")                                                     \
        for (int q = 0; q < 3; ++q)                                           \
            t2[q] = v2[q*3+0]*ux + v2[q*3+1]*uy + v2[q*3+2]*uz;               \
        float s1 = v1[0]*ux + v1[1]*uy + v1[2]*uz;                            \
        float s2 = t2[0]*ux + t2[1]*uy + t2[2]*uz;                            \
        acc[0] += fn[0]*v0 + fn[4]*s1 + fn[9]*s2;                             \
        _Pragma("unroll")                                                     \
        for (int m = 0; m < 3; ++m)                                           \
            acc[1+m] += fn[1]*v0*u[m] + fn[3]*v1[m] + fn[6]*s1*u[m]           \
                      + fn[8]*t2[m];                                          \
        _Pragma("unroll")                                                     \
        for (int q = 0; q < 3; ++q) {                                         \
            float ca = fn[2]*v0*u[q] + fn[5]*v1[q] + fn[10]*t2[q];            \
            _Pragma("unroll")                                                 \
            for (int bb = 0; bb < 3; ++bb)                                    \
                acc[4 + q*3 + bb] += ca*u[bb] + fn[7]*v2[q*3 + bb];           \
        }                                                                     \
    }

    int p = start + h;
    for (; p + 2 < end; p += 4) {       // 2 edges in flight per half-lane
        EDGE_BODY(p);
        EDGE_BODY(p + 2);
    }
    if (p < end) EDGE_BODY(p);
#undef EDGE_BODY

    // combine the two edge-halves
    #pragma unroll
    for (int q = 0; q < 13; ++q)
        acc[q] += __shfl_xor(acc[q], 32);

    if (h == 0) {
        float* out0 = out;
        float* out1 = out + N_ATOMS * C;
        float* out2 = out + N_ATOMS * C * 4;
        out0[a*C + c] = acc[0];
        #pragma unroll
        for (int m = 0; m < 3; ++m) out1[(a*C + c)*3 + m] = acc[1+m];
        #pragma unroll
        for (int q = 0; q < 9; ++q) out2[(a*C + c)*9 + q] = acc[4+q];
    }
}

// ---------------- fallback: round-0 atomic path ----------------
__global__ __launch_bounds__(256) void edge_atomic_kernel(
    const float* __restrict__ x0, const float* __restrict__ x1,
    const float* __restrict__ x2, const float* __restrict__ pos,
    const float* __restrict__ W, const float* __restrict__ b,
    const int* __restrict__ idx_i, const int* __restrict__ idx_j,
    float* __restrict__ out)
{
    int tid = blockIdx.x * blockDim.x + threadIdx.x;
    int e = tid >> 5;
    int c = tid & 31;
    if (e >= N_EDGES) return;
    int i = idx_i[e], j = idx_j[e];
    float rx = pos[3*j+0] - pos[3*i+0];
    float ry = pos[3*j+1] - pos[3*i+1];
    float rz = pos[3*j+2] - pos[3*i+2];
    float d  = sqrtf(rx*rx + ry*ry + rz*rz + 1e-12f);
    float invd = 1.0f / d;
    float ux = rx*invd, uy = ry*invd, uz = rz*invd;
    const float PI = 3.14159265358979323846f;
    const float RC = 5.0f;
    float fc   = 0.5f * (cosf(PI * fminf(d, RC) / RC) + 1.0f);
    float pref = sqrtf(2.0f / RC) * invd * fc;
    float phase = PI * d / RC;
    float rbf[NB];
    #pragma unroll
    for (int nb = 0; nb < NB; ++nb) rbf[nb] = pref * sinf((float)(nb+1) * phase);
    float fn[NCOMB];
    #pragma unroll
    for (int k = 0; k < NCOMB; ++k) {
        float acc = b[k*C + c];
        #pragma unroll
        for (int nb = 0; nb < NB; ++nb) acc += rbf[nb] * W[(k*NB + nb)*C + c];
        fn[k] = acc * (1.0f / 32.0f);
    }
    float v0 = x0[j*C + c];
    float v1[3], v2[9];
    #pragma unroll
    for (int m = 0; m < 3; ++m) v1[m] = x1[(j*C + c)*3 + m];
    #pragma unroll
    for (int m = 0; m < 9; ++m) v2[m] = x2[(j*C + c)*9 + m];
    float u[3] = {ux, uy, uz};
    float t2[3];
    #pragma unroll
    for (int q = 0; q < 3; ++q)
        t2[q] = v2[q*3+0]*ux + v2[q*3+1]*uy + v2[q*3+2]*uz;
    float s1 = v1[0]*ux + v1[1]*uy + v1[2]*uz;
    float s2 = t2[0]*ux + t2[1]*uy + t2[2]*uz;
    float* out0 = out;
    float* out1 = out + N_ATOMS * C;
    float* out2 = out + N_ATOMS * C * 4;
    atomicAdd(&out0[i*C + c], fn[0]*v0 + fn[4]*s1 + fn[9]*s2);
    #pragma unroll
    for (int m = 0; m < 3; ++m)
        atomicAdd(&out1[(i*C + c)*3 + m],
                  fn[1]*v0*u[m] + fn[3]*v1[m] + fn[6]*s1*u[m] + fn[8]*t2[m]);
    #pragma unroll
    for (int q = 0; q < 3; ++q) {
        float ca = fn[2]*v0*u[q] + fn[5]*v1[q] + fn[10]*t2[q];
        #pragma unroll
        for (int bb = 0; bb < 3; ++bb)
            atomicAdd(&out2[(i*C + c)*9 + q*3 + bb], ca*u[bb] + fn[7]*v2[q*3 + bb]);
    }
}

extern "C" void kernel_launch(void* const* d_in, const int* in_sizes, int n_in,
                              void* d_out, int out_size, void* d_ws, size_t ws_size,
                              hipStream_t stream) {
    const float* x0    = (const float*)d_in[0];
    const float* x1    = (const float*)d_in[1];
    const float* x2    = (const float*)d_in[2];
    const float* pos   = (const float*)d_in[3];
    const float* W     = (const float*)d_in[4];
    const float* b     = (const float*)d_in[5];
    const int*   idx_i = (const int*)d_in[6];
    const int*   idx_j = (const int*)d_in[7];
    float* out = (float*)d_out;

    if (ws_size >= WS_NEEDED) {
        char* ws = (char*)d_ws;
        int*   counts  = (int*)(ws + WS_COUNTS);
        int*   offsets = (int*)(ws + WS_OFFSETS);
        int*   cursor  = (int*)(ws + WS_CURSOR);
        float* edata   = (float*)(ws + WS_EDATA);

        hipMemsetAsync(counts, 0, N_ATOMS * sizeof(int), stream);

        int eb = 256, eg = (N_EDGES + eb - 1) / eb;
        hist_kernel<<<eg, eb, 0, stream>>>(idx_i, counts);
        scan_kernel<<<1, 256, 0, stream>>>(counts, offsets, cursor);
        prep_scatter_kernel<<<eg, eb, 0, stream>>>(pos, idx_i, idx_j, cursor, edata);

        int waves_per_block = 256 / 64;
        int grid = (N_ATOMS + waves_per_block - 1) / waves_per_block;
        gather_kernel<<<grid, 256, 0, stream>>>(x0, x1, x2, W, b,
                                                offsets, edata, out);
    } else {
        hipMemsetAsync(d_out, 0, (size_t)out_size * sizeof(float), stream);
        int total_threads = N_EDGES * 32;
        int block = 256;
        int grid = (total_threads + block - 1) / block;
        edge_atomic_kernel<<<grid, block, 0, stream>>>(
            x0, x1, x2, pos, W, b, idx_i, idx_j, out);
    }
}